// Round 2
// baseline (253.530 us; speedup 1.0000x reference)
//
#include <hip/hip_runtime.h>
#include <hip/hip_bf16.h>

// Encoding layer. B=16, C=512, N=4096, K=32.
// Grid: 512 blocks (b = blk>>5, chunk = blk&31; 128 tokens/block, 4 groups of 32).
// 256 threads = 4 waves. LDS ~47.5 KiB -> 3 blocks/CU (12 waves/CU).
// Register-pipelined staging; partials to d_ws + reduce kernel (no global atomics).

#define B_ 16
#define C_ 512
#define N_ 4096
#define K_ 32
#define XCPAD 40   // n-stride of XC tile (bf16); 80 B rows, b128 16B-aligned

typedef __attribute__((ext_vector_type(8))) short short8;
typedef __attribute__((ext_vector_type(16))) float floatx16;

__device__ inline unsigned short f2bf(float f) {
    union { float f; unsigned u; } v; v.f = f;
    unsigned r = v.u + 0x7FFFu + ((v.u >> 16) & 1u);  // RNE
    return (unsigned short)(r >> 16);
}
__device__ inline float bf2f(short s) {
    union { unsigned u; float f; } v; v.u = ((unsigned)(unsigned short)s) << 16;
    return v.f;
}

template <int USE_WS>
__global__ __launch_bounds__(256, 3)
void enc_kernel(const float* __restrict__ x, const float* __restrict__ cw,
                const float* __restrict__ scale, float* __restrict__ outp)
{
    __shared__ unsigned short XC[C_ * XCPAD];   // x tile bf16 [c][n], 40960 B
    __shared__ float Spart[32][33];             // atomically-accumulated S, 4224 B
    __shared__ unsigned short Wl[K_ * XCPAD];   // softmax weights bf16 [k][n], 2560 B
    __shared__ float xsqp[4][32];               // per-wave ||x_n||^2 partials
    __shared__ float csq[K_];
    __shared__ float scl[K_];
    __shared__ float wsumL[K_];

    const int tid  = threadIdx.x;
    const int wave = tid >> 6;
    const int lane = tid & 63;
    const int l31  = lane & 31;
    const int lh   = lane >> 5;

    const int b     = blockIdx.x >> 5;
    const int chunk = blockIdx.x & 31;
    const long xbase = (long)b * C_ * N_;

    // ---- preamble: scale, c_sq, Spart zero ----
    if (tid < K_) scl[tid] = scale[tid];
    for (int i = tid; i < 32 * 33; i += 256) ((float*)Spart)[i] = 0.f;
    {
        const int k = tid >> 3, p = tid & 7;
        const float4* cwr = (const float4*)(cw + k * C_ + p * 64);
        float s = 0.f;
        #pragma unroll
        for (int i = 0; i < 16; ++i) {
            float4 v = cwr[i];
            s += v.x*v.x + v.y*v.y + v.z*v.z + v.w*v.w;
        }
        s += __shfl_xor(s, 1); s += __shfl_xor(s, 2); s += __shfl_xor(s, 4);
        if (p == 0) csq[k] = s;
    }

    // ---- GEMM1 B-frags: cw^T for this wave's 128-c range (kept in regs) ----
    short8 cwf[8];
    #pragma unroll
    for (int s = 0; s < 8; ++s) {
        const float* p = cw + l31 * C_ + wave * 128 + s * 16 + lh * 8;
        short8 f;
        #pragma unroll
        for (int j = 0; j < 8; ++j) f[j] = (short)f2bf(p[j]);
        cwf[s] = f;
    }

    floatx16 acc[4];           // GEMM2 accum: wave's 4 c-tiles of 32
    #pragma unroll
    for (int t = 0; t < 4; ++t)
        #pragma unroll
        for (int i = 0; i < 16; ++i) acc[t][i] = 0.f;
    float wsum_r = 0.f;        // per-lane partial of sum_n W[k=l31][n]

    // staging thread mapping
    const int c0 = tid >> 3;   // 0..31 (c mod 32)
    const int nq = tid & 7;    // n-quad
    const float* xg = x + xbase + (long)c0 * N_ + chunk * 128 + nq * 4;

    float4 bufA[4], bufB[4];
    // issue quarter q of group g into buf
    #define ISSUEQ(buf, g, q)                                            \
        { _Pragma("unroll")                                              \
          for (int j = 0; j < 4; ++j)                                    \
              buf[j] = *(const float4*)(xg + (long)(32 * ((q)*4 + j)) * N_ + (g) * 32); }

    ISSUEQ(bufA, 0, 0);
    __syncthreads();

    for (int g = 0; g < 4; ++g) {
        // ---- staging: pipelined fp32->bf16 LDS + ||x||^2 ----
        float sq0 = 0.f, sq1 = 0.f, sq2 = 0.f, sq3 = 0.f;
        #pragma unroll
        for (int q = 0; q < 4; ++q) {
            float4* cur = (q & 1) ? bufB : bufA;
            float4* nxt = (q & 1) ? bufA : bufB;
            if (q < 3)      { ISSUEQ(nxt, g, q + 1); }
            else if (g < 3) { ISSUEQ(nxt, g + 1, 0); }   // in flight across GEMM phases
            #pragma unroll
            for (int j = 0; j < 4; ++j) {
                const int c = c0 + 32 * (q * 4 + j);
                const float4 v = cur[j];
                sq0 += v.x*v.x; sq1 += v.y*v.y; sq2 += v.z*v.z; sq3 += v.w*v.w;
                const unsigned lo = (unsigned)f2bf(v.x) | ((unsigned)f2bf(v.y) << 16);
                const unsigned hi = (unsigned)f2bf(v.z) | ((unsigned)f2bf(v.w) << 16);
                *(uint2*)&XC[c * XCPAD + nq * 4] = make_uint2(lo, hi);
            }
        }
        #pragma unroll
        for (int m = 8; m <= 32; m <<= 1) {
            sq0 += __shfl_xor(sq0, m); sq1 += __shfl_xor(sq1, m);
            sq2 += __shfl_xor(sq2, m); sq3 += __shfl_xor(sq3, m);
        }
        if ((lane >> 3) == 0) {
            xsqp[wave][nq * 4 + 0] = sq0; xsqp[wave][nq * 4 + 1] = sq1;
            xsqp[wave][nq * 4 + 2] = sq2; xsqp[wave][nq * 4 + 3] = sq3;
        }
        __syncthreads();

        // ---- GEMM1: S[n][k] += X^T @ cw^T over wave's 128-c range ----
        {
            floatx16 S;
            #pragma unroll
            for (int i = 0; i < 16; ++i) S[i] = 0.f;
            #pragma unroll
            for (int s = 0; s < 8; ++s) {
                const int cb = wave * 128 + s * 16 + lh * 8;
                short8 a;
                #pragma unroll
                for (int j = 0; j < 8; ++j)
                    a[j] = (short)XC[(cb + j) * XCPAD + l31];
                S = __builtin_amdgcn_mfma_f32_32x32x16_bf16(a, cwf[s], S, 0, 0, 0);
            }
            #pragma unroll
            for (int r = 0; r < 16; ++r) {
                const int n = (r & 3) + 8 * (r >> 2) + 4 * lh;
                atomicAdd(&Spart[n][l31], S[r]);        // ds_add_f32
            }
        }
        __syncthreads();

        // ---- softmax over k (fp32); zero Spart for next group ----
        {
            const int n  = tid >> 3;
            const int kq = tid & 7;
            const float xq = xsqp[0][n] + xsqp[1][n] + xsqp[2][n] + xsqp[3][n];
            float L[4];
            #pragma unroll
            for (int i = 0; i < 4; ++i) {
                const int k = kq * 4 + i;
                const float s2 = Spart[n][k];
                Spart[n][k] = 0.f;
                L[i] = scl[k] * (xq - 2.f * s2 + csq[k]);
            }
            float m = fmaxf(fmaxf(L[0], L[1]), fmaxf(L[2], L[3]));
            m = fmaxf(m, __shfl_xor(m, 1));
            m = fmaxf(m, __shfl_xor(m, 2));
            m = fmaxf(m, __shfl_xor(m, 4));
            float e[4], sum = 0.f;
            #pragma unroll
            for (int i = 0; i < 4; ++i) { e[i] = __expf(L[i] - m); sum += e[i]; }
            sum += __shfl_xor(sum, 1); sum += __shfl_xor(sum, 2); sum += __shfl_xor(sum, 4);
            const float inv = 1.f / sum;
            #pragma unroll
            for (int i = 0; i < 4; ++i)
                Wl[(kq * 4 + i) * XCPAD + n] = f2bf(e[i] * inv);
        }
        __syncthreads();

        // ---- GEMM2: acc[k][c] += W @ X^T ; wsum from A-frags ----
        {
            short8 aw[2];
            #pragma unroll
            for (int sub = 0; sub < 2; ++sub)
                aw[sub] = *(const short8*)&Wl[l31 * XCPAD + sub * 16 + lh * 8];
            float ws = 0.f;
            #pragma unroll
            for (int sub = 0; sub < 2; ++sub)
                #pragma unroll
                for (int j = 0; j < 8; ++j) ws += bf2f(aw[sub][j]);
            wsum_r += ws;
            #pragma unroll
            for (int t4 = 0; t4 < 4; ++t4) {
                const int crow = (wave * 4 + t4) * 32 + l31;
                #pragma unroll
                for (int sub = 0; sub < 2; ++sub) {
                    const short8 bx = *(const short8*)&XC[crow * XCPAD + sub * 16 + lh * 8];
                    acc[t4] = __builtin_amdgcn_mfma_f32_32x32x16_bf16(aw[sub], bx, acc[t4], 0, 0, 0);
                }
            }
        }
        __syncthreads();   // protect XC/Wl/Spart/xsqp before next staging
    }

    // ---- wsum broadcast ----
    wsum_r += __shfl_xor(wsum_r, 32);
    if (wave == 0 && lh == 0) wsumL[l31] = wsum_r;
    __syncthreads();

    // ---- epilogue ----
    float* dst = USE_WS ? (outp + (size_t)blockIdx.x * K_ * C_)
                        : (outp + (size_t)b * K_ * C_);
    #pragma unroll
    for (int t4 = 0; t4 < 4; ++t4) {
        const int c = (wave * 4 + t4) * 32 + l31;
        #pragma unroll
        for (int r = 0; r < 16; ++r) {
            const int k = (r & 3) + 8 * (r >> 2) + 4 * lh;
            const float val = acc[t4][r] - wsumL[k] * cw[k * C_ + c];
            if (USE_WS) dst[k * C_ + c] = val;
            else        atomicAdd(dst + k * C_ + c, val);
        }
    }
}

// out[b][k][c] = sum_{ch<32} part[b*32+ch][k][c];  grid 256 x 256, float4
__global__ __launch_bounds__(256)
void reduce_kernel(const float4* __restrict__ part, float4* __restrict__ out)
{
    const int gid = blockIdx.x * 256 + threadIdx.x;   // 0..65535
    const int bb  = gid >> 12;                        // 4096 float4 per batch
    const int i4  = gid & 4095;
    const float4* p = part + ((size_t)bb * 32) * 4096 + i4;
    float4 s = make_float4(0.f, 0.f, 0.f, 0.f);
    #pragma unroll
    for (int ch = 0; ch < 32; ++ch) {
        const float4 v = p[(size_t)ch * 4096];
        s.x += v.x; s.y += v.y; s.z += v.z; s.w += v.w;
    }
    out[gid] = s;
}

extern "C" void kernel_launch(void* const* d_in, const int* in_sizes, int n_in,
                              void* d_out, int out_size, void* d_ws, size_t ws_size,
                              hipStream_t stream) {
    const float* x     = (const float*)d_in[0];
    const float* cw    = (const float*)d_in[1];
    const float* scale = (const float*)d_in[2];
    float* out = (float*)d_out;

    const size_t ws_need = (size_t)512 * K_ * C_ * sizeof(float);  // 32 MiB
    if (ws_size >= ws_need) {
        float* part = (float*)d_ws;
        hipLaunchKernelGGL(enc_kernel<1>, dim3(B_ * 32), dim3(256), 0, stream,
                           x, cw, scale, part);
        hipLaunchKernelGGL(reduce_kernel, dim3(256), dim3(256), 0, stream,
                           (const float4*)part, (float4*)out);
    } else {
        hipMemsetAsync(out, 0, (size_t)out_size * sizeof(float), stream);
        hipLaunchKernelGGL(enc_kernel<0>, dim3(B_ * 32), dim3(256), 0, stream,
                           x, cw, scale, out);
    }
}

// Round 3
// 218.435 us; speedup vs baseline: 1.1607x; 1.1607x over previous
//
#include <hip/hip_runtime.h>

// Encoding layer. B=16, C=512, N=4096, K=32.
// Grid: 512 blocks (b = blk>>5, chunk = blk&31; 128 tokens/block).
// 256 threads = 4 waves; each wave owns one 32-token group for GEMM1/softmax,
// and a 128-wide c-range for GEMM2. Only 2 barriers per block.
// GEMM1: A = cw^T (LDS, staged once), B = x direct from global (2 full lines/inst).
// GEMM2: A = W (LDS), B = x re-read from global (L2-hot). Partials -> d_ws + reduce.

#define B_ 16
#define C_ 512
#define N_ 4096
#define K_ 32
#define CWS 520   // cwT row stride (u16): 1040 B = 65*16 -> rows 16B-aligned
#define WLS 40    // Wl  row stride (u16):   80 B = 5*16

typedef __attribute__((ext_vector_type(8))) short short8;
typedef __attribute__((ext_vector_type(16))) float floatx16;

__device__ inline unsigned short f2bf(float f) {
    union { float f; unsigned u; } v; v.f = f;
    unsigned r = v.u + 0x7FFFu + ((v.u >> 16) & 1u);  // RNE
    return (unsigned short)(r >> 16);
}
__device__ inline float bf2f(unsigned short s) {
    union { unsigned u; float f; } v; v.u = ((unsigned)s) << 16;
    return v.f;
}

template <int USE_WS>
__global__ __launch_bounds__(256, 3)
void enc_kernel(const float* __restrict__ x, const float* __restrict__ cw,
                const float* __restrict__ scale, float* __restrict__ outp)
{
    __shared__ unsigned short cwT[K_ * CWS];      // cw bf16 [k][c], 33280 B
    __shared__ unsigned short Wl[4][K_ * WLS];    // softmax w bf16 [g][k][n], 10240 B
    __shared__ float csq[K_];
    __shared__ float scl[K_];

    const int tid  = threadIdx.x;
    const int wave = tid >> 6;
    const int lane = tid & 63;
    const int l31  = lane & 31;
    const int lh   = lane >> 5;

    const int b     = blockIdx.x >> 5;
    const int chunk = blockIdx.x & 31;
    const float* xb = x + (long)b * C_ * N_;

    // ---- init: scale, cw -> cwT bf16 + csq ----
    if (tid < K_) scl[tid] = scale[tid];
    {
        const int k = tid >> 3, p = tid & 7;          // k row, 64-c slice
        const float4* src = (const float4*)(cw + k * C_ + p * 64);
        float s = 0.f;
        #pragma unroll
        for (int i = 0; i < 16; ++i) {
            const float4 v = src[i];
            s += v.x*v.x + v.y*v.y + v.z*v.z + v.w*v.w;
            const unsigned lo = (unsigned)f2bf(v.x) | ((unsigned)f2bf(v.y) << 16);
            const unsigned hi = (unsigned)f2bf(v.z) | ((unsigned)f2bf(v.w) << 16);
            *(uint2*)&cwT[k * CWS + p * 64 + i * 4] = make_uint2(lo, hi);
        }
        s += __shfl_xor(s, 1); s += __shfl_xor(s, 2); s += __shfl_xor(s, 4);
        if (p == 0) csq[k] = s;
    }
    __syncthreads();

    // ================= GEMM1 + softmax (per-wave, barrier-free) =================
    // wave's 32-token group: n0..n0+31; lane l31 = token col, lh = kk-half.
    const int n0 = chunk * 128 + wave * 32;
    const float* xg = xb + n0 + l31;

    floatx16 S;
    #pragma unroll
    for (int i = 0; i < 16; ++i) S[i] = 0.f;
    float xsq = 0.f;

    #pragma unroll
    for (int sp = 0; sp < 16; ++sp) {          // 16 step-pairs, K-step = 16 c
        float xv[16];
        #pragma unroll
        for (int u = 0; u < 16; ++u) {         // batch 16 independent dword loads
            const int c = sp * 32 + (u >> 3) * 16 + lh * 8 + (u & 7);
            xv[u] = xg[(long)c * N_];
        }
        #pragma unroll
        for (int h = 0; h < 2; ++h) {
            const int s = sp * 2 + h;
            const short8 af = *(const short8*)&cwT[l31 * CWS + s * 16 + lh * 8];
            short8 bx;
            #pragma unroll
            for (int j = 0; j < 8; ++j) {
                const float v = xv[h * 8 + j];
                xsq += v * v;
                bx[j] = (short)f2bf(v);
            }
            S = __builtin_amdgcn_mfma_f32_32x32x16_bf16(af, bx, S, 0, 0, 0);
        }
    }
    xsq += __shfl_xor(xsq, 32);                // combine lh-halves (same token)

    // softmax over k: lane holds 16 of 32 logits (lh picks the k-half)
    {
        float L[16], mx = -3.4e38f;
        #pragma unroll
        for (int r = 0; r < 16; ++r) {
            const int k = (r & 3) + 8 * (r >> 2) + 4 * lh;
            L[r] = scl[k] * (xsq - 2.f * S[r] + csq[k]);
            mx = fmaxf(mx, L[r]);
        }
        mx = fmaxf(mx, __shfl_xor(mx, 32));
        float sum = 0.f;
        #pragma unroll
        for (int r = 0; r < 16; ++r) { L[r] = __expf(L[r] - mx); sum += L[r]; }
        sum += __shfl_xor(sum, 32);
        const float inv = 1.f / sum;
        #pragma unroll
        for (int r = 0; r < 16; ++r) {
            const int k = (r & 3) + 8 * (r >> 2) + 4 * lh;
            Wl[wave][k * WLS + l31] = f2bf(L[r] * inv);
        }
    }
    __syncthreads();   // the ONE data barrier: Wl handoff to all waves

    // ================= GEMM2: enc[k][c] = sum_n W[k][n] x[n][c] =================
    // A-frags: 8 steps over n=128 (g = st>>1, half = st&1), shared by all c-tiles.
    short8 aw[8];
    #pragma unroll
    for (int st = 0; st < 8; ++st)
        aw[st] = *(const short8*)&Wl[st >> 1][l31 * WLS + (st & 1) * 16 + lh * 8];

    // wsum[k] via ones-column MFMA (every wave; rows match acc rows)
    floatx16 wacc;
    #pragma unroll
    for (int i = 0; i < 16; ++i) wacc[i] = 0.f;
    {
        short8 ones;
        #pragma unroll
        for (int j = 0; j < 8; ++j) ones[j] = (short)0x3F80;
        #pragma unroll
        for (int st = 0; st < 8; ++st)
            wacc = __builtin_amdgcn_mfma_f32_32x32x16_bf16(aw[st], ones, wacc, 0, 0, 0);
    }

    float* dst = USE_WS ? (outp + (size_t)blockIdx.x * K_ * C_)
                        : (outp + (size_t)b * K_ * C_);

    #pragma unroll
    for (int t = 0; t < 4; ++t) {
        const int c = wave * 128 + t * 32 + l31;          // B col = c
        const float* xgc = xb + (long)c * N_ + chunk * 128 + lh * 8;
        floatx16 acc;
        #pragma unroll
        for (int i = 0; i < 16; ++i) acc[i] = 0.f;
        #pragma unroll
        for (int st = 0; st < 8; ++st) {
            const int noff = (st >> 1) * 32 + (st & 1) * 16;
            const float4 v0 = *(const float4*)(xgc + noff);
            const float4 v1 = *(const float4*)(xgc + noff + 4);
            short8 bx;
            bx[0] = (short)f2bf(v0.x); bx[1] = (short)f2bf(v0.y);
            bx[2] = (short)f2bf(v0.z); bx[3] = (short)f2bf(v0.w);
            bx[4] = (short)f2bf(v1.x); bx[5] = (short)f2bf(v1.y);
            bx[6] = (short)f2bf(v1.z); bx[7] = (short)f2bf(v1.w);
            acc = __builtin_amdgcn_mfma_f32_32x32x16_bf16(aw[st], bx, acc, 0, 0, 0);
        }
        // epilogue for this c-tile: val = acc - wsum[k]*cw[k][c]
        #pragma unroll
        for (int r = 0; r < 16; ++r) {
            const int k = (r & 3) + 8 * (r >> 2) + 4 * lh;
            const float cwv = bf2f(cwT[k * CWS + c]);
            const float val = acc[r] - wacc[r] * cwv;
            if (USE_WS) dst[k * C_ + c] = val;
            else        atomicAdd(dst + k * C_ + c, val);
        }
    }
}

// out[b][k][c] = sum_{ch<32} part[b*32+ch][k][c];  grid 256 x 256, float4
__global__ __launch_bounds__(256)
void reduce_kernel(const float4* __restrict__ part, float4* __restrict__ out)
{
    const int gid = blockIdx.x * 256 + threadIdx.x;   // 0..65535
    const int bb  = gid >> 12;                        // 4096 float4 per batch
    const int i4  = gid & 4095;
    const float4* p = part + ((size_t)bb * 32) * 4096 + i4;
    float4 s = make_float4(0.f, 0.f, 0.f, 0.f);
    #pragma unroll
    for (int ch = 0; ch < 32; ++ch) {
        const float4 v = p[(size_t)ch * 4096];
        s.x += v.x; s.y += v.y; s.z += v.z; s.w += v.w;
    }
    out[gid] = s;
}

extern "C" void kernel_launch(void* const* d_in, const int* in_sizes, int n_in,
                              void* d_out, int out_size, void* d_ws, size_t ws_size,
                              hipStream_t stream) {
    const float* x     = (const float*)d_in[0];
    const float* cw    = (const float*)d_in[1];
    const float* scale = (const float*)d_in[2];
    float* out = (float*)d_out;

    const size_t ws_need = (size_t)512 * K_ * C_ * sizeof(float);  // 32 MiB
    if (ws_size >= ws_need) {
        float* part = (float*)d_ws;
        hipLaunchKernelGGL(enc_kernel<1>, dim3(B_ * 32), dim3(256), 0, stream,
                           x, cw, scale, part);
        hipLaunchKernelGGL(reduce_kernel, dim3(256), dim3(256), 0, stream,
                           (const float4*)part, (float4*)out);
    } else {
        hipMemsetAsync(out, 0, (size_t)out_size * sizeof(float), stream);
        hipLaunchKernelGGL(enc_kernel<0>, dim3(B_ * 32), dim3(256), 0, stream,
                           x, cw, scale, out);
    }
}

// Round 4
// 217.005 us; speedup vs baseline: 1.1683x; 1.0066x over previous
//
#include <hip/hip_runtime.h>

// Encoding layer. B=16, C=512, N=4096, K=32.
// Grid: 512 blocks (b = blk>>5, chunk = blk&31; 128 tokens/block).
// 256 threads = 4 waves; wave owns one 32-token group for GEMM1/softmax and a
// 128-wide c-range for GEMM2. 2 barriers/block. Deep register-ring pipelines:
// GEMM1 keeps 32-48 scalar loads in flight, GEMM2 keeps ~6 float4-pairs in
// flight (L2-hot re-read). Partials -> d_ws + reduce kernel.

#define B_ 16
#define C_ 512
#define N_ 4096
#define K_ 32
#define CWS 520   // cwT row stride (u16): 1040 B -> rows 16B-aligned
#define WLS 40    // Wl  row stride (u16):   80 B

typedef __attribute__((ext_vector_type(8))) short short8;
typedef __attribute__((ext_vector_type(16))) float floatx16;

__device__ inline unsigned short f2bf(float f) {
    union { float f; unsigned u; } v; v.f = f;
    unsigned r = v.u + 0x7FFFu + ((v.u >> 16) & 1u);  // RNE
    return (unsigned short)(r >> 16);
}
__device__ inline float bf2f(unsigned short s) {
    union { unsigned u; float f; } v; v.u = ((unsigned)s) << 16;
    return v.f;
}

template <int USE_WS>
__global__ __launch_bounds__(256, 2)
void enc_kernel(const float* __restrict__ x, const float* __restrict__ cw,
                const float* __restrict__ scale, float* __restrict__ outp)
{
    __shared__ unsigned short cwT[K_ * CWS];      // cw bf16 [k][c], 33280 B
    __shared__ unsigned short Wl[4][K_ * WLS];    // softmax w bf16 [g][k][n], 10240 B
    __shared__ float csq[K_];
    __shared__ float scl[K_];

    const int tid  = threadIdx.x;
    const int wave = tid >> 6;
    const int lane = tid & 63;
    const int l31  = lane & 31;
    const int lh   = lane >> 5;

    const int b     = blockIdx.x >> 5;
    const int chunk = blockIdx.x & 31;
    const float* xb = x + (long)b * C_ * N_;

    // ---- GEMM1 ring prefetch: 3 stages issued BEFORE init (overlap staging) ----
    const int n0 = chunk * 128 + wave * 32;
    const float* xg = xb + n0 + l31;
    float xv[3][16];
#define G1LOAD(st_, sp_)                                                       \
    { _Pragma("unroll")                                                        \
      for (int u = 0; u < 16; ++u)                                             \
          xv[st_][u] = xg[(long)((sp_) * 32 + (u >> 3) * 16 + lh * 8 + (u & 7)) * N_]; }
    G1LOAD(0, 0)
    G1LOAD(1, 1)
    G1LOAD(2, 2)

    // ---- init: scale, cw -> cwT bf16 + csq ----
    if (tid < K_) scl[tid] = scale[tid];
    {
        const int k = tid >> 3, p = tid & 7;          // k row, 64-c slice
        const float4* src = (const float4*)(cw + k * C_ + p * 64);
        float s = 0.f;
        #pragma unroll
        for (int i = 0; i < 16; ++i) {
            const float4 v = src[i];
            s += v.x*v.x + v.y*v.y + v.z*v.z + v.w*v.w;
            const unsigned lo = (unsigned)f2bf(v.x) | ((unsigned)f2bf(v.y) << 16);
            const unsigned hi = (unsigned)f2bf(v.z) | ((unsigned)f2bf(v.w) << 16);
            *(uint2*)&cwT[k * CWS + p * 64 + i * 4] = make_uint2(lo, hi);
        }
        s += __shfl_xor(s, 1); s += __shfl_xor(s, 2); s += __shfl_xor(s, 4);
        if (p == 0) csq[k] = s;
    }
    __syncthreads();

    // ================= GEMM1: S[n][k] = X^T @ cw^T (pipelined) =================
    floatx16 S;
    #pragma unroll
    for (int i = 0; i < 16; ++i) S[i] = 0.f;
    float xsq = 0.f;

    #pragma unroll
    for (int sp = 0; sp < 16; ++sp) {
        const int st = sp % 3;
        #pragma unroll
        for (int h = 0; h < 2; ++h) {
            const int s = sp * 2 + h;
            const short8 af = *(const short8*)&cwT[l31 * CWS + s * 16 + lh * 8];
            short8 bx;
            #pragma unroll
            for (int j = 0; j < 8; ++j) {
                const float v = xv[st][h * 8 + j];
                xsq += v * v;
                bx[j] = (short)f2bf(v);
            }
            S = __builtin_amdgcn_mfma_f32_32x32x16_bf16(af, bx, S, 0, 0, 0);
        }
        if (sp + 3 < 16) G1LOAD(st, sp + 3)
    }
    xsq += __shfl_xor(xsq, 32);                // combine lh-halves (same token)

    // ---- softmax over k: lane holds 16 of 32 logits (lh picks the k-half) ----
    {
        float L[16], mx = -3.4e38f;
        #pragma unroll
        for (int r = 0; r < 16; ++r) {
            const int k = (r & 3) + 8 * (r >> 2) + 4 * lh;
            L[r] = scl[k] * (xsq - 2.f * S[r] + csq[k]);
            mx = fmaxf(mx, L[r]);
        }
        mx = fmaxf(mx, __shfl_xor(mx, 32));
        float sum = 0.f;
        #pragma unroll
        for (int r = 0; r < 16; ++r) { L[r] = __expf(L[r] - mx); sum += L[r]; }
        sum += __shfl_xor(sum, 32);
        const float inv = 1.f / sum;
        #pragma unroll
        for (int r = 0; r < 16; ++r) {
            const int k = (r & 3) + 8 * (r >> 2) + 4 * lh;
            Wl[wave][k * WLS + l31] = f2bf(L[r] * inv);
        }
    }

    // ---- GEMM2 ring prefetch: 6 steps issued BEFORE the Wl barrier ----
    float4 bv[6][2];
#define G2LOAD(bi_, i_)                                                        \
    { const int t_ = (i_) >> 3, st_ = (i_) & 7;                                \
      const int c_ = wave * 128 + t_ * 32 + l31;                               \
      const int no_ = (st_ >> 1) * 32 + (st_ & 1) * 16 + lh * 8;               \
      const float* p_ = xb + (long)c_ * N_ + chunk * 128 + no_;                \
      bv[bi_][0] = *(const float4*)p_;                                         \
      bv[bi_][1] = *(const float4*)(p_ + 4); }
    G2LOAD(0, 0)
    G2LOAD(1, 1)
    G2LOAD(2, 2)
    G2LOAD(3, 3)
    G2LOAD(4, 4)
    G2LOAD(5, 5)

    __syncthreads();   // the ONE data barrier: Wl handoff to all waves

    // ================= GEMM2: enc[k][c] = sum_n W[k][n] x[n][c] =================
    short8 aw[8];
    #pragma unroll
    for (int st = 0; st < 8; ++st)
        aw[st] = *(const short8*)&Wl[st >> 1][l31 * WLS + (st & 1) * 16 + lh * 8];

    // wsum[k] via ones-column MFMA (latency filler while prefetches land)
    floatx16 wacc;
    #pragma unroll
    for (int i = 0; i < 16; ++i) wacc[i] = 0.f;
    {
        short8 ones;
        #pragma unroll
        for (int j = 0; j < 8; ++j) ones[j] = (short)0x3F80;
        #pragma unroll
        for (int st = 0; st < 8; ++st)
            wacc = __builtin_amdgcn_mfma_f32_32x32x16_bf16(aw[st], ones, wacc, 0, 0, 0);
    }

    floatx16 acc[4];
    #pragma unroll
    for (int t = 0; t < 4; ++t)
        #pragma unroll
        for (int i = 0; i < 16; ++i) acc[t][i] = 0.f;

    #pragma unroll
    for (int i = 0; i < 32; ++i) {             // i = t*8 + st
        const int bi = i % 6;
        const int t  = i >> 3, st = i & 7;
        const float4 v0 = bv[bi][0];
        const float4 v1 = bv[bi][1];
        short8 bx;
        bx[0] = (short)f2bf(v0.x); bx[1] = (short)f2bf(v0.y);
        bx[2] = (short)f2bf(v0.z); bx[3] = (short)f2bf(v0.w);
        bx[4] = (short)f2bf(v1.x); bx[5] = (short)f2bf(v1.y);
        bx[6] = (short)f2bf(v1.z); bx[7] = (short)f2bf(v1.w);
        acc[t] = __builtin_amdgcn_mfma_f32_32x32x16_bf16(aw[st], bx, acc[t], 0, 0, 0);
        if (i + 6 < 32) G2LOAD(bi, i + 6)
    }

    // ---- epilogue: val = acc - wsum[k]*cw[k][c] ----
    float* dst = USE_WS ? (outp + (size_t)blockIdx.x * K_ * C_)
                        : (outp + (size_t)b * K_ * C_);
    #pragma unroll
    for (int t = 0; t < 4; ++t) {
        const int c = wave * 128 + t * 32 + l31;
        #pragma unroll
        for (int r = 0; r < 16; ++r) {
            const int k = (r & 3) + 8 * (r >> 2) + 4 * lh;
            const float cwv = bf2f(cwT[k * CWS + c]);
            const float val = acc[t][r] - wacc[r] * cwv;
            if (USE_WS) dst[k * C_ + c] = val;
            else        atomicAdd(dst + k * C_ + c, val);
        }
    }
}

// out[b][k][c] = sum_{ch<32} part[b*32+ch][k][c];  grid 256 x 256, float4
__global__ __launch_bounds__(256)
void reduce_kernel(const float4* __restrict__ part, float4* __restrict__ out)
{
    const int gid = blockIdx.x * 256 + threadIdx.x;   // 0..65535
    const int bb  = gid >> 12;                        // 4096 float4 per batch
    const int i4  = gid & 4095;
    const float4* p = part + ((size_t)bb * 32) * 4096 + i4;
    float4 s = make_float4(0.f, 0.f, 0.f, 0.f);
    #pragma unroll
    for (int ch = 0; ch < 32; ++ch) {
        const float4 v = p[(size_t)ch * 4096];
        s.x += v.x; s.y += v.y; s.z += v.z; s.w += v.w;
    }
    out[gid] = s;
}

extern "C" void kernel_launch(void* const* d_in, const int* in_sizes, int n_in,
                              void* d_out, int out_size, void* d_ws, size_t ws_size,
                              hipStream_t stream) {
    const float* x     = (const float*)d_in[0];
    const float* cw    = (const float*)d_in[1];
    const float* scale = (const float*)d_in[2];
    float* out = (float*)d_out;

    const size_t ws_need = (size_t)512 * K_ * C_ * sizeof(float);  // 32 MiB
    if (ws_size >= ws_need) {
        float* part = (float*)d_ws;
        hipLaunchKernelGGL(enc_kernel<1>, dim3(B_ * 32), dim3(256), 0, stream,
                           x, cw, scale, part);
        hipLaunchKernelGGL(reduce_kernel, dim3(256), dim3(256), 0, stream,
                           (const float4*)part, (float4*)out);
    } else {
        hipMemsetAsync(out, 0, (size_t)out_size * sizeof(float), stream);
        hipLaunchKernelGGL(enc_kernel<0>, dim3(B_ * 32), dim3(256), 0, stream,
                           x, cw, scale, out);
    }
}

// Round 5
// 216.137 us; speedup vs baseline: 1.1730x; 1.0040x over previous
//
#include <hip/hip_runtime.h>

// Encoding layer. B=16, C=512, N=4096, K=32.
// Grid: 512 blocks (b = blk>>5, chunk = blk&31; 128 tokens/block).
// 256 threads = 4 waves. GEMM1: x staged to LDS in 8 double-buffered c-groups
// of 64 rows; every global read is a contiguous 512 B row-slice (float4/lane).
// GEMM2 re-reads x from global (L3-hot). Partials -> d_ws + reduce kernel.

#define B_ 16
#define C_ 512
#define N_ 4096
#define K_ 32
#define CWS 520   // cwT row stride (u16): 1040 B
#define WLS 40    // Wl  row stride (u16):   80 B
#define XCP 132   // XC  row stride (u16):  264 B (b64-aligned writes)

typedef __attribute__((ext_vector_type(8))) short short8;
typedef __attribute__((ext_vector_type(16))) float floatx16;

__device__ inline unsigned short f2bf(float f) {
    union { float f; unsigned u; } v; v.f = f;
    unsigned r = v.u + 0x7FFFu + ((v.u >> 16) & 1u);  // RNE
    return (unsigned short)(r >> 16);
}
__device__ inline float bf2f(unsigned short s) {
    union { unsigned u; float f; } v; v.u = ((unsigned)s) << 16;
    return v.f;
}

template <int USE_WS>
__global__ __launch_bounds__(256, 2)
void enc_kernel(const float* __restrict__ x, const float* __restrict__ cw,
                const float* __restrict__ scale, float* __restrict__ outp)
{
    __shared__ unsigned short cwT[K_ * CWS];     // cw bf16 [k][c], 33280 B
    __shared__ unsigned short XC[2][64 * XCP];   // x bf16 [grp][c][n], 33792 B
    __shared__ unsigned short Wl[4][K_ * WLS];   // softmax w bf16 [g][k][n], 10240 B
    __shared__ float xsqp[4][128];               // ||x_n||^2 wave-partials, 2048 B
    __shared__ float csq[K_];
    __shared__ float scl[K_];

    const int tid  = threadIdx.x;
    const int wave = tid >> 6;
    const int lane = tid & 63;
    const int l31  = lane & 31;
    const int lh   = lane >> 5;

    const int b     = blockIdx.x >> 5;
    const int chunk = blockIdx.x & 31;
    const float* xb = x + (long)b * C_ * N_;

    // staging mapping: thread = (r = tid>>5, p = tid&31); per group it loads
    // 8 rows (c = g*64 + i*8 + r), each as float4 covering tokens p*4..p*4+3.
    const int r = tid >> 5;
    const int p = tid & 31;
    const float* xrow = xb + chunk * 128 + p * 4;

    float4 sA[8], sB[8];
#define XISSUE(buf_, g_)                                                       \
    { _Pragma("unroll")                                                        \
      for (int i = 0; i < 8; ++i)                                              \
          buf_[i] = *(const float4*)(xrow + (long)((g_) * 64 + i * 8 + r) * N_); }

    float xs0 = 0.f, xs1 = 0.f, xs2 = 0.f, xs3 = 0.f;
#define XWRITE(buf_, dst_)                                                     \
    { _Pragma("unroll")                                                        \
      for (int i = 0; i < 8; ++i) {                                            \
          const float4 v = buf_[i];                                            \
          xs0 += v.x * v.x; xs1 += v.y * v.y;                                  \
          xs2 += v.z * v.z; xs3 += v.w * v.w;                                  \
          const unsigned lo = (unsigned)f2bf(v.x) | ((unsigned)f2bf(v.y) << 16);\
          const unsigned hi = (unsigned)f2bf(v.z) | ((unsigned)f2bf(v.w) << 16);\
          *(uint2*)&XC[dst_][(i * 8 + r) * XCP + p * 4] = make_uint2(lo, hi);  \
      } }

    // prefetch groups 0,1 before cwT staging (overlaps its latency)
    XISSUE(sA, 0)
    XISSUE(sB, 1)

    // ---- init: scale, cw -> cwT bf16 + csq ----
    if (tid < K_) scl[tid] = scale[tid];
    {
        const int k = tid >> 3, q = tid & 7;          // k row, 64-c slice
        const float4* src = (const float4*)(cw + k * C_ + q * 64);
        float s = 0.f;
        #pragma unroll
        for (int i = 0; i < 16; ++i) {
            const float4 v = src[i];
            s += v.x*v.x + v.y*v.y + v.z*v.z + v.w*v.w;
            const unsigned lo = (unsigned)f2bf(v.x) | ((unsigned)f2bf(v.y) << 16);
            const unsigned hi = (unsigned)f2bf(v.z) | ((unsigned)f2bf(v.w) << 16);
            *(uint2*)&cwT[k * CWS + q * 64 + i * 4] = make_uint2(lo, hi);
        }
        s += __shfl_xor(s, 1); s += __shfl_xor(s, 2); s += __shfl_xor(s, 4);
        if (q == 0) csq[k] = s;
    }

    XWRITE(sA, 0)          // group 0 -> XC[0]
    __syncthreads();       // cwT + XC[0] ready

    // ================= GEMM1: S[k][n] = cw @ X, c-group pipelined =============
    floatx16 S;
    #pragma unroll
    for (int i = 0; i < 16; ++i) S[i] = 0.f;

    #pragma unroll
    for (int g = 0; g < 8; ++g) {
        if (g + 2 < 8) {
            if ((g & 1) == 0) { XISSUE(sA, g + 2) } else { XISSUE(sB, g + 2) }
        }
        // 4 MFMA steps over this 64-c group; wave's tokens = wave*32 + l31
        #pragma unroll
        for (int s = 0; s < 4; ++s) {
            const short8 af = *(const short8*)&cwT[l31 * CWS + (g * 4 + s) * 16 + lh * 8];
            short8 bx;
            #pragma unroll
            for (int j = 0; j < 8; ++j)
                bx[j] = (short)XC[g & 1][(s * 16 + lh * 8 + j) * XCP + wave * 32 + l31];
            S = __builtin_amdgcn_mfma_f32_32x32x16_bf16(af, bx, S, 0, 0, 0);
        }
        if (g + 1 < 8) {
            if ((g & 1) == 0) { XWRITE(sB, (g + 1) & 1) } else { XWRITE(sA, (g + 1) & 1) }
        }
        if (g < 7) __syncthreads();
    }

    // ---- xsq: pair-reduce (r, r^1) via shfl, then per-wave LDS partials ----
    xs0 += __shfl_xor(xs0, 32); xs1 += __shfl_xor(xs1, 32);
    xs2 += __shfl_xor(xs2, 32); xs3 += __shfl_xor(xs3, 32);
    if (lane < 32) {
        xsqp[wave][l31 * 4 + 0] = xs0; xsqp[wave][l31 * 4 + 1] = xs1;
        xsqp[wave][l31 * 4 + 2] = xs2; xsqp[wave][l31 * 4 + 3] = xs3;
    }

    // ---- GEMM2 ring prefetch (address-independent of softmax) ----
    float4 bv[6][2];
#define G2LOAD(bi_, i_)                                                        \
    { const int t_ = (i_) >> 3, st_ = (i_) & 7;                                \
      const int c_ = wave * 128 + t_ * 32 + l31;                               \
      const int no_ = (st_ >> 1) * 32 + (st_ & 1) * 16 + lh * 8;               \
      const float* p_ = xb + (long)c_ * N_ + chunk * 128 + no_;                \
      bv[bi_][0] = *(const float4*)p_;                                         \
      bv[bi_][1] = *(const float4*)(p_ + 4); }
    G2LOAD(0, 0)
    G2LOAD(1, 1)
    G2LOAD(2, 2)
    G2LOAD(3, 3)
    G2LOAD(4, 4)
    G2LOAD(5, 5)

    __syncthreads();   // xsqp ready

    // ---- softmax over k: lane = token wave*32+l31, regs = 16 k's per lh ----
    {
        const int n = wave * 32 + l31;
        const float xq = xsqp[0][n] + xsqp[1][n] + xsqp[2][n] + xsqp[3][n];
        float L[16], mx = -3.4e38f;
        #pragma unroll
        for (int rr = 0; rr < 16; ++rr) {
            const int k = (rr & 3) + 8 * (rr >> 2) + 4 * lh;
            L[rr] = scl[k] * (xq - 2.f * S[rr] + csq[k]);
            mx = fmaxf(mx, L[rr]);
        }
        mx = fmaxf(mx, __shfl_xor(mx, 32));
        float sum = 0.f;
        #pragma unroll
        for (int rr = 0; rr < 16; ++rr) { L[rr] = __expf(L[rr] - mx); sum += L[rr]; }
        sum += __shfl_xor(sum, 32);
        const float inv = 1.f / sum;
        #pragma unroll
        for (int rr = 0; rr < 16; ++rr) {
            const int k = (rr & 3) + 8 * (rr >> 2) + 4 * lh;
            Wl[wave][k * WLS + l31] = f2bf(L[rr] * inv);
        }
    }
    __syncthreads();   // Wl handoff

    // ================= GEMM2: enc[k][c] = sum_n W[k][n] x[n][c] =================
    short8 aw[8];
    #pragma unroll
    for (int st = 0; st < 8; ++st)
        aw[st] = *(const short8*)&Wl[st >> 1][l31 * WLS + (st & 1) * 16 + lh * 8];

    floatx16 wacc;
    #pragma unroll
    for (int i = 0; i < 16; ++i) wacc[i] = 0.f;
    {
        short8 ones;
        #pragma unroll
        for (int j = 0; j < 8; ++j) ones[j] = (short)0x3F80;
        #pragma unroll
        for (int st = 0; st < 8; ++st)
            wacc = __builtin_amdgcn_mfma_f32_32x32x16_bf16(aw[st], ones, wacc, 0, 0, 0);
    }

    floatx16 acc[4];
    #pragma unroll
    for (int t = 0; t < 4; ++t)
        #pragma unroll
        for (int i = 0; i < 16; ++i) acc[t][i] = 0.f;

    #pragma unroll
    for (int i = 0; i < 32; ++i) {             // i = t*8 + st
        const int bi = i % 6;
        const int t  = i >> 3, st = i & 7;
        const float4 v0 = bv[bi][0];
        const float4 v1 = bv[bi][1];
        short8 bx;
        bx[0] = (short)f2bf(v0.x); bx[1] = (short)f2bf(v0.y);
        bx[2] = (short)f2bf(v0.z); bx[3] = (short)f2bf(v0.w);
        bx[4] = (short)f2bf(v1.x); bx[5] = (short)f2bf(v1.y);
        bx[6] = (short)f2bf(v1.z); bx[7] = (short)f2bf(v1.w);
        acc[t] = __builtin_amdgcn_mfma_f32_32x32x16_bf16(aw[st], bx, acc[t], 0, 0, 0);
        if (i + 6 < 32) G2LOAD(bi, i + 6)
    }

    // ---- epilogue: val = acc - wsum[k]*cw[k][c] ----
    float* dst = USE_WS ? (outp + (size_t)blockIdx.x * K_ * C_)
                        : (outp + (size_t)b * K_ * C_);
    #pragma unroll
    for (int t = 0; t < 4; ++t) {
        const int c = wave * 128 + t * 32 + l31;
        #pragma unroll
        for (int rr = 0; rr < 16; ++rr) {
            const int k = (rr & 3) + 8 * (rr >> 2) + 4 * lh;
            const float cwv = bf2f(cwT[k * CWS + c]);
            const float val = acc[t][rr] - wacc[rr] * cwv;
            if (USE_WS) dst[k * C_ + c] = val;
            else        atomicAdd(dst + k * C_ + c, val);
        }
    }
}

// out[b][k][c] = sum_{ch<32} part[b*32+ch][k][c];  grid 256 x 256, float4
__global__ __launch_bounds__(256)
void reduce_kernel(const float4* __restrict__ part, float4* __restrict__ out)
{
    const int gid = blockIdx.x * 256 + threadIdx.x;   // 0..65535
    const int bb  = gid >> 12;                        // 4096 float4 per batch
    const int i4  = gid & 4095;
    const float4* p = part + ((size_t)bb * 32) * 4096 + i4;
    float4 s = make_float4(0.f, 0.f, 0.f, 0.f);
    #pragma unroll
    for (int ch = 0; ch < 32; ++ch) {
        const float4 v = p[(size_t)ch * 4096];
        s.x += v.x; s.y += v.y; s.z += v.z; s.w += v.w;
    }
    out[gid] = s;
}

extern "C" void kernel_launch(void* const* d_in, const int* in_sizes, int n_in,
                              void* d_out, int out_size, void* d_ws, size_t ws_size,
                              hipStream_t stream) {
    const float* x     = (const float*)d_in[0];
    const float* cw    = (const float*)d_in[1];
    const float* scale = (const float*)d_in[2];
    float* out = (float*)d_out;

    const size_t ws_need = (size_t)512 * K_ * C_ * sizeof(float);  // 32 MiB
    if (ws_size >= ws_need) {
        float* part = (float*)d_ws;
        hipLaunchKernelGGL(enc_kernel<1>, dim3(B_ * 32), dim3(256), 0, stream,
                           x, cw, scale, part);
        hipLaunchKernelGGL(reduce_kernel, dim3(256), dim3(256), 0, stream,
                           (const float4*)part, (float4*)out);
    } else {
        hipMemsetAsync(out, 0, (size_t)out_size * sizeof(float), stream);
        hipLaunchKernelGGL(enc_kernel<0>, dim3(B_ * 32), dim3(256), 0, stream,
                           x, cw, scale, out);
    }
}